// Round 1
// baseline (323.282 us; speedup 1.0000x reference)
//
#include <hip/hip_runtime.h>

// TypedCoords2Volume: per-atom Gaussian splat into [B, NTYPES, 120,120,120].
// Memory-bound on zeroing the 304 MB output; splat itself is ~1.1M atomics.

#define BOX    120
#define NTYPES 11
#define DHALF  2
#define WIN    5      // 2*DHALF+1
#define WVOX   125    // WIN^3
#define BOX3   (BOX * BOX * BOX)

// ---------------------------------------------------------------------------
// Zero-fill: float4 stores, grid-stride. Handles non-multiple-of-4 tail.
// ---------------------------------------------------------------------------
__global__ void zero_kernel(float* __restrict__ out, long long n) {
    long long n4 = n >> 2;
    float4* out4 = reinterpret_cast<float4*>(out);
    long long i = (long long)blockIdx.x * blockDim.x + threadIdx.x;
    long long stride = (long long)gridDim.x * blockDim.x;
    float4 z = make_float4(0.f, 0.f, 0.f, 0.f);
    for (; i < n4; i += stride) out4[i] = z;
    // tail (n % 4 elements), done by first few threads of block 0
    if (blockIdx.x == 0) {
        long long tail_start = n4 << 2;
        long long t = tail_start + threadIdx.x;
        if (t < n) out[t] = 0.f;
    }
}

// ---------------------------------------------------------------------------
// Splat: 128 threads per atom (one per window voxel, 3 idle).
// Each thread: load atom coords (broadcast within its group, L1-cached),
// resolve type via linear searchsorted over 11 offsets, compute Gaussian,
// atomicAdd into the typed volume.
// ---------------------------------------------------------------------------
__global__ void splat_kernel(const float* __restrict__ coords,
                             const int*  __restrict__ num_atoms_of_type,
                             const int*  __restrict__ offsets,
                             float* __restrict__ out,
                             int batch, int natoms) {
    int gid  = blockIdx.x * blockDim.x + threadIdx.x;
    int atom = gid >> 7;          // 128 slots per atom
    int j    = gid & 127;
    if (atom >= batch * natoms || j >= WVOX) return;

    int b = atom / natoms;
    int i = atom - b * natoms;

    const float* c = coords + ((long long)b * natoms + i) * 3;
    float x = c[0], y = c[1], z = c[2];

    const int* off = offsets          + b * NTYPES;
    const int* num = num_atoms_of_type + b * NTYPES;

    // t = clip(searchsorted(off, i, side='right') - 1, 0, NTYPES-1)
    int t = 0;
#pragma unroll
    for (int k = 1; k < NTYPES; ++k) {
        if (off[k] <= i) t = k;
    }
    bool valid = (i >= off[t]) && (i < off[t] + num[t]);
    if (!valid) return;

    int bx = (int)floorf(x);
    int by = (int)floorf(y);
    int bz = (int)floorf(z);

    int wx = j / 25;
    int rem = j - wx * 25;
    int wy = rem / 5;
    int wz = rem - wy * 5;

    int cx = bx + wx - DHALF;
    int cy = by + wy - DHALF;
    int cz = bz + wz - DHALF;
    if ((unsigned)cx >= (unsigned)BOX ||
        (unsigned)cy >= (unsigned)BOX ||
        (unsigned)cz >= (unsigned)BOX) return;

    float dx = (float)cx - x;
    float dy = (float)cy - y;
    float dz = (float)cz - z;
    float r2 = dx * dx + dy * dy + dz * dz;
    float val = expf(-r2);   // RES = 1.0 -> exp(-r2 / 1)

    int idx = (b * NTYPES + t) * BOX3 + cx * (BOX * BOX) + cy * BOX + cz;
    atomicAdd(&out[idx], val);
}

// ---------------------------------------------------------------------------
extern "C" void kernel_launch(void* const* d_in, const int* in_sizes, int n_in,
                              void* d_out, int out_size, void* d_ws, size_t ws_size,
                              hipStream_t stream) {
    const float* coords = (const float*)d_in[0];
    const int*   num    = (const int*)d_in[1];
    const int*   off    = (const int*)d_in[2];
    float*       out    = (float*)d_out;

    // derive shapes from input sizes (NTYPES is fixed at 11 by the module)
    int batch  = in_sizes[1] / NTYPES;            // [B, NTYPES]
    int natoms = in_sizes[0] / (3 * batch);       // [B, NATOMS*3]

    // 1) zero the output volume (must complete before scatter; same stream)
    zero_kernel<<<8192, 256, 0, stream>>>(out, (long long)out_size);

    // 2) scatter Gaussian splats
    int total_threads = batch * natoms * 128;
    int blocks = (total_threads + 255) / 256;
    splat_kernel<<<blocks, 256, 0, stream>>>(coords, num, off, out,
                                             batch, natoms);
}